// Round 7
// baseline (155.555 us; speedup 1.0000x reference)
//
#include <hip/hip_runtime.h>
#include <hip/hip_bf16.h>
#include <math.h>

#define INPUT_DIM 256
#define OUT_DIM   256
#define NDEG      8                    // degree+1
#define KTOT      (INPUT_DIM * NDEG)   // 2048
#define NROWS     (16 * 2048)          // 32768

#define BM  64                         // block tile M (1 row-group, 4 waves of 64x64)
#define BK  64                         // 8 inputs * 8 degrees per K-chunk
#define NK  (KTOT / BK)                // 32
#define SLICE 4096                     // per-wave B slice: 64 o * 64 k bf16 = 8 KB

typedef __bf16 bf16x8 __attribute__((ext_vector_type(8)));
typedef float  f32x16 __attribute__((ext_vector_type(16)));

// ---------------------------------------------------------------------------
// Kernel 1: reorder + swizzle coeffs C[i][o][d] (fp32) -> Bt_sw (bf16).
// Per-(kc, wave-slice) layout, the exact linear LDS image for global_load_lds:
//   dst = kc*16384 + g*4096 + p*512 + ol*8 + r
//   (g = o>>6 wave slice, p = i&7 input-in-chunk, ol = o&63, r = d)
// ---------------------------------------------------------------------------
__global__ __launch_bounds__(256) void reorder_coeffs(const float* __restrict__ C,
                                                      __bf16* __restrict__ Bt) {
    int g_ = blockIdx.x * 256 + threadIdx.x;   // 65536 = 256 i * 256 o
    int i = g_ >> 8;
    int o = g_ & 255;
    const float4* src = (const float4*)(C + (size_t)i * (OUT_DIM * NDEG) + o * NDEG);
    float4 a = src[0];
    float4 b = src[1];
    bf16x8 v;
    v[0] = (__bf16)a.x; v[1] = (__bf16)a.y; v[2] = (__bf16)a.z; v[3] = (__bf16)a.w;
    v[4] = (__bf16)b.x; v[5] = (__bf16)b.y; v[6] = (__bf16)b.z; v[7] = (__bf16)b.w;
    int kc = i >> 3;          // K-chunk
    int p  = i & 7;           // input-in-chunk
    int g  = o >> 6;          // wave slice
    int ol = o & 63;          // o within slice
    size_t dst = (size_t)kc * (4 * SLICE) + g * SLICE + p * 512 + ol * 8;
    *(bf16x8*)(Bt + dst) = v;   // 16B-aligned
}

// tanh + physicists' Hermite recurrence -> bf16x8 A-fragment (operand layout:
// one input's 8 degrees = one lane's 8 k-values for mfma_32x32x16_bf16)
__device__ __forceinline__ bf16x8 featurize(float xs) {
    float e = __expf(2.0f * xs);            // tanh(x)=1-2/(e^{2x}+1), robust all x
    float t = 1.0f - 2.0f / (e + 1.0f);
    bf16x8 v;
    float hm2 = 1.0f;                       // H_0
    float hm1 = 2.0f * t;                   // H_1
    v[0] = (__bf16)hm2;
    v[1] = (__bf16)hm1;
    #pragma unroll
    for (int d = 2; d < 8; ++d) {
        float h = 2.0f * t * hm1 - 2.0f * (float)(d - 1) * hm2;
        v[d] = (__bf16)h;
        hm2 = hm1; hm1 = h;
    }
    return v;
}

// ---------------------------------------------------------------------------
// Kernel 2 (Round 7): barrier-free per-wave pipeline.
//  - A featurized DIRECTLY into mfma_32x32x16 A-operand registers
//    (A[m=lane&31][k=(lane>>5)*8+j]; lane's 8 k = one input's 8 degrees).
//    No A LDS traffic, no __syncthreads anywhere in the K-loop.
//  - B: each wave DMAs its private 8 KB slice (glds w16) into its own LDS
//    dbuf; explicit s_waitcnt vmcnt(0) guards ds_read vs DMA completion
//    (the glds it drains was issued one full MFMA phase earlier).
//  - Wave tile 64x64 = 2x2 frags of 32x32x16 (2495 TF shape, m119).
// Block 256 thr (4 waves), tile 64x256, grid 512 = 2 blocks/CU (LDS 64 KB).
// ---------------------------------------------------------------------------
__global__ __launch_bounds__(256, 2) void hermite_mfma(const float* __restrict__ x,
                                                       const __bf16* __restrict__ Bt,
                                                       float* __restrict__ out) {
    __shared__ __align__(16) __bf16 Blds[4 * 2 * SLICE];   // [wave][buf][4096] = 64 KB

    const int tid  = threadIdx.x;
    const int bm   = blockIdx.x;       // 0..511
    const int wave = tid >> 6;         // 0..3  (wc = wave*64)
    const int lane = tid & 63;
    const int l31  = lane & 31;
    const int h    = lane >> 5;        // k-group half

    // x rows for this lane's A fragments (mi=0: +0, mi=1: +32)
    const float* xr0 = x + (size_t)(bm * BM + l31) * INPUT_DIM + h;
    const float* xr1 = xr0 + 32 * INPUT_DIM;

    // B: this wave's slice stream
    const __bf16* bsrc = Bt + (size_t)wave * SLICE + lane * 8;   // + kc*4*SLICE per chunk
    __bf16* bl = &Blds[wave * 2 * SLICE];
    const int loff = lane * 8;         // per-lane 16 B, matches glds lane*size rule

    f32x16 acc[2][2] = {};

    // ---- prologue: xs + B slice for chunk 0 ----
    float xs0[4], xs1[4];
    #pragma unroll
    for (int s = 0; s < 4; ++s) { xs0[s] = xr0[2 * s]; xs1[s] = xr1[2 * s]; }
    #pragma unroll
    for (int i = 0; i < 8; ++i)
        __builtin_amdgcn_global_load_lds(
            (const __attribute__((address_space(1))) void*)(bsrc + i * 512),
            (__attribute__((address_space(3))) void*)(bl + i * 512 + loff),
            16, 0, 0);

    for (int kc = 0; kc < NK; ++kc) {
        const int buf = kc & 1;

        // ---- A fragments in-register (consuming xs forces the vmcnt drain) ----
        bf16x8 af0[4], af1[4];
        #pragma unroll
        for (int s = 0; s < 4; ++s) { af0[s] = featurize(xs0[s]); af1[s] = featurize(xs1[s]); }

        // ---- guard: B slice (buf) DMA must have landed before ds_read ----
        __builtin_amdgcn_s_waitcnt(0x0f70);   // vmcnt(0), lgkm/exp don't-care

        // ---- B fragments for the whole chunk: 8 ds_read_b128 ----
        bf16x8 bfr[4][2];
        #pragma unroll
        for (int s = 0; s < 4; ++s)
            #pragma unroll
            for (int ni = 0; ni < 2; ++ni)
                bfr[s][ni] = *(const bf16x8*)(bl + buf * SLICE + (2 * s + h) * 512
                                              + (ni * 32 + l31) * 8);

        // ---- prefetch chunk kc+1 (B DMA + xs), in flight across the MFMAs ----
        if (kc + 1 < NK) {
            const __bf16* g = bsrc + (size_t)(kc + 1) * (4 * SLICE);
            #pragma unroll
            for (int i = 0; i < 8; ++i)
                __builtin_amdgcn_global_load_lds(
                    (const __attribute__((address_space(1))) void*)(g + i * 512),
                    (__attribute__((address_space(3))) void*)(bl + (buf ^ 1) * SLICE + i * 512 + loff),
                    16, 0, 0);
            #pragma unroll
            for (int s = 0; s < 4; ++s) {
                xs0[s] = xr0[(kc + 1) * 8 + 2 * s];
                xs1[s] = xr1[(kc + 1) * 8 + 2 * s];
            }
        }

        // ---- MFMA: 4 k-steps of 16, 2x2 frags of 32x32x16 ----
        #pragma unroll
        for (int s = 0; s < 4; ++s) {
            acc[0][0] = __builtin_amdgcn_mfma_f32_32x32x16_bf16(af0[s], bfr[s][0], acc[0][0], 0, 0, 0);
            acc[0][1] = __builtin_amdgcn_mfma_f32_32x32x16_bf16(af0[s], bfr[s][1], acc[0][1], 0, 0, 0);
            acc[1][0] = __builtin_amdgcn_mfma_f32_32x32x16_bf16(af1[s], bfr[s][0], acc[1][0], 0, 0, 0);
            acc[1][1] = __builtin_amdgcn_mfma_f32_32x32x16_bf16(af1[s], bfr[s][1], acc[1][1], 0, 0, 0);
        }
    }

    // ---- epilogue: 32x32 C/D layout col=lane&31, row=(reg&3)+8*(reg>>2)+4*h
    //      (m74/m101-verified) ----
    #pragma unroll
    for (int mi = 0; mi < 2; ++mi)
        #pragma unroll
        for (int ni = 0; ni < 2; ++ni) {
            #pragma unroll
            for (int r = 0; r < 16; ++r) {
                int rl  = (r & 3) + 8 * (r >> 2) + 4 * h;
                int row = bm * BM + mi * 32 + rl;
                out[(size_t)row * OUT_DIM + wave * 64 + ni * 32 + l31] = acc[mi][ni][r];
            }
        }
}

// ---------------------------------------------------------------------------
extern "C" void kernel_launch(void* const* d_in, const int* in_sizes, int n_in,
                              void* d_out, int out_size, void* d_ws, size_t ws_size,
                              hipStream_t stream) {
    const float* x = (const float*)d_in[0];          // [16,2048,256] fp32
    const float* C = (const float*)d_in[1];          // [256,256,8]  fp32
    float* out = (float*)d_out;                      // [16,2048,256] fp32
    __bf16* Bt = (__bf16*)d_ws;                      // swizzled [32][4][4096] bf16, 1 MB

    reorder_coeffs<<<dim3((INPUT_DIM * OUT_DIM) / 256), dim3(256), 0, stream>>>(C, Bt);
    hermite_mfma<<<dim3(NROWS / BM), dim3(256), 0, stream>>>(x, Bt, out);
}